// Round 16
// baseline (107.229 us; speedup 1.0000x reference)
//
#include <hip/hip_runtime.h>

#define ALPHA 0.2f

typedef __attribute__((ext_vector_type(8))) short short8;
typedef __attribute__((ext_vector_type(8))) unsigned short ushort8;
typedef __attribute__((ext_vector_type(4))) float f32x4;

__device__ __forceinline__ float bf2f(unsigned short u) {
    return __uint_as_float(((unsigned int)u) << 16);
}
__device__ __forceinline__ unsigned short f2bf(float f) {
    unsigned int x = __float_as_uint(f);
    unsigned int r = (x + 0x7fffu + ((x >> 16) & 1u)) >> 16;   // RNE
    return (unsigned short)r;
}

// Per-wave fp32-vs-bf16 detection on x's low u16 bf16-exponent plausibility.
__device__ __forceinline__ int detect_is32(const unsigned int* xw) {
    int lane = threadIdx.x & 63;
    unsigned int u = xw[lane];
    unsigned int e = (u >> 7) & 0xffu;
    unsigned long long b = __ballot(e >= 0x58u && e <= 0x90u);
    return (__popcll(b) < 40) ? 1 : 0;
}

// ---------------------------------------------------------------------------
// Kernel 1 (fused prep) — x-plane staging DELETED (gemm now converts x
// in-register during A-staging):
//   blocks [0,64):   W -> bf16 TRANSPOSED [H][F][C], LDS-tiled
//   blocks [64,...): adjacency bitmask atomics (self-detects int64/int32)
// Block 0 publishes flags[0] (fp32-ness of float inputs).
// ---------------------------------------------------------------------------
__global__ __launch_bounds__(256) void prep(const void* __restrict__ x_raw,
                                            const void* __restrict__ W_raw,
                                            const int* __restrict__ ei, int E, int N,
                                            unsigned short* __restrict__ wt_hi,
                                            unsigned long long* __restrict__ adj,
                                            int* __restrict__ flags) {
    int bid = blockIdx.x, tid = threadIdx.x;

    if (bid < 64) {
        __shared__ unsigned short lh[64][65];
        int is32 = detect_is32((const unsigned int*)x_raw);
        if (bid == 0 && tid == 0) flags[0] = is32;
        int head = bid >> 3;
        int c0 = (bid & 7) * 64;
        int cl = tid >> 2;
        int fc = (tid & 3) * 16;

        size_t ebase = ((size_t)head * 512 + c0 + cl) * 64 + fc;
        if (is32) {
            const float* Wf = (const float*)W_raw;
#pragma unroll
            for (int v4 = 0; v4 < 4; v4++) {
                float4 v = *(const float4*)(Wf + ebase + v4 * 4);
                lh[fc + v4 * 4 + 0][cl] = f2bf(v.x);
                lh[fc + v4 * 4 + 1][cl] = f2bf(v.y);
                lh[fc + v4 * 4 + 2][cl] = f2bf(v.z);
                lh[fc + v4 * 4 + 3][cl] = f2bf(v.w);
            }
        } else {
            const unsigned short* Wb = (const unsigned short*)W_raw;
            ushort8 u0 = *(const ushort8*)(Wb + ebase);
            ushort8 u1 = *(const ushort8*)(Wb + ebase + 8);
#pragma unroll
            for (int k = 0; k < 8; k++) {
                lh[fc + k][cl] = u0[k];
                lh[fc + 8 + k][cl] = u1[k];
            }
        }
        __syncthreads();
        int fl = tid >> 2;
        int cc = (tid & 3) * 16;
        ushort8 oh0, oh1;
#pragma unroll
        for (int k = 0; k < 8; k++) {
            oh0[k] = lh[fl][cc + k];
            oh1[k] = lh[fl][cc + 8 + k];
        }
        size_t o = (size_t)head * 32768 + (size_t)fl * 512 + c0 + cc;
        *(ushort8*)(wt_hi + o)     = oh0;
        *(ushort8*)(wt_hi + o + 8) = oh1;
    } else {
        int lane = tid & 63;
        unsigned long long nz = __ballot(ei[2 * lane + 1] != 0);
        int is64 = (nz == 0ull) ? 1 : 0;
        int t = (bid - 64) * 256 + tid;
        int words = N >> 6;
        if (t < E) {
            int r = is64 ? ei[2 * t]       : ei[t];
            int c = is64 ? ei[2 * (E + t)] : ei[E + t];
            atomicOr(&adj[(size_t)r * words + (c >> 6)], 1ull << (c & 63));
        } else if (t < E + N) {
            int i = t - E;
            atomicOr(&adj[(size_t)i * words + (i >> 6)], 1ull << (i & 63));
        }
    }
}

// ---------------------------------------------------------------------------
// Kernel 2: MFMA GEMM, pure bf16: h = bf16(x) * wt. BK=64, shared LDS
// double-buffer (frozen r8/r12 skeleton), K = 512 -> 8 iters.
// A is loaded DIRECTLY from x (fp32 or bf16 per flag) and converted
// in-register with the same RNE f2bf — MFMA inputs bit-identical to r15.
// ---------------------------------------------------------------------------
#define LROW 72
__global__ __launch_bounds__(256) void gemm_mfma(const void* __restrict__ x_raw,
                                                 const unsigned short* __restrict__ wth,
                                                 const void* __restrict__ a_raw,
                                                 unsigned short* __restrict__ h2b,
                                                 float* __restrict__ s_src2,
                                                 float* __restrict__ s_dst2,
                                                 const int* __restrict__ flags) {
    __shared__ unsigned short sA[2][64 * LROW];
    __shared__ unsigned short sB[2][64 * LROW];

    int head = blockIdx.y;
    int row0 = blockIdx.x * 64;
    int tid = threadIdx.x;
    int w = tid >> 6, lane = tid & 63;
    int m = lane & 15, quad = lane >> 4;
    int srow = tid >> 2, sc = tid & 3;

    int gis32 = flags[0];
    size_t baseA = (size_t)(row0 + srow) * 512 + sc * 8;   // element index into x
    size_t baseB = (size_t)head * 32768 + (size_t)srow * 512 + sc * 8;

    int ldsw  = srow * LROW + sc * 8;
    int ldsAr = (w * 16 + m) * LROW + quad * 8;

    f32x4 acc[4] = {f32x4{0.f, 0.f, 0.f, 0.f}, f32x4{0.f, 0.f, 0.f, 0.f},
                    f32x4{0.f, 0.f, 0.f, 0.f}, f32x4{0.f, 0.f, 0.f, 0.f}};

    // iter c (0..7): k-offset c*64. A converted in-register (RNE, bit-identical
    // to the staged-plane path).
#define LOADSET(Aa, Ab, Ba, Bb, c)                                         \
    {                                                                      \
        size_t ko = (size_t)(c) * 64;                                      \
        if (gis32) {                                                       \
            const float* xf = (const float*)x_raw;                         \
            float4 v0 = *(const float4*)(xf + baseA + ko);                 \
            float4 v1 = *(const float4*)(xf + baseA + ko + 4);             \
            float4 v2 = *(const float4*)(xf + baseA + ko + 32);            \
            float4 v3 = *(const float4*)(xf + baseA + ko + 36);            \
            Aa[0] = f2bf(v0.x); Aa[1] = f2bf(v0.y); Aa[2] = f2bf(v0.z); Aa[3] = f2bf(v0.w); \
            Aa[4] = f2bf(v1.x); Aa[5] = f2bf(v1.y); Aa[6] = f2bf(v1.z); Aa[7] = f2bf(v1.w); \
            Ab[0] = f2bf(v2.x); Ab[1] = f2bf(v2.y); Ab[2] = f2bf(v2.z); Ab[3] = f2bf(v2.w); \
            Ab[4] = f2bf(v3.x); Ab[5] = f2bf(v3.y); Ab[6] = f2bf(v3.z); Ab[7] = f2bf(v3.w); \
        } else {                                                           \
            const unsigned short* xb = (const unsigned short*)x_raw;       \
            Aa = *(const ushort8*)(xb + baseA + ko);                       \
            Ab = *(const ushort8*)(xb + baseA + ko + 32);                  \
        }                                                                  \
        Ba = *(const ushort8*)(wth + baseB + ko);                          \
        Bb = *(const ushort8*)(wth + baseB + ko + 32);                     \
    }

#define WRITESET(buf, Aa, Ab, Ba, Bb)                                      \
    {                                                                      \
        *(ushort8*)&sA[buf][ldsw]      = Aa;                               \
        *(ushort8*)&sA[buf][ldsw + 32] = Ab;                               \
        *(ushort8*)&sB[buf][ldsw]      = Ba;                               \
        *(ushort8*)&sB[buf][ldsw + 32] = Bb;                               \
    }

#define COMPUTE(buf)                                                       \
    {                                                                      \
        short8 af0 = *(const short8*)&sA[buf][ldsAr];                      \
        short8 af1 = *(const short8*)&sA[buf][ldsAr + 32];                 \
        _Pragma("unroll")                                                  \
        for (int t = 0; t < 4; t++) {                                      \
            int bo = (t * 16 + m) * LROW + quad * 8;                       \
            short8 bf0 = *(const short8*)&sB[buf][bo];                     \
            short8 bf1 = *(const short8*)&sB[buf][bo + 32];                \
            acc[t] = __builtin_amdgcn_mfma_f32_16x16x32_bf16(af0, bf0, acc[t], 0, 0, 0); \
            acc[t] = __builtin_amdgcn_mfma_f32_16x16x32_bf16(af1, bf1, acc[t], 0, 0, 0); \
        }                                                                  \
    }

    ushort8 a0a, a0b, b0a, b0b;    // even set
    ushort8 a1a, a1b, b1a, b1b;    // odd set

    LOADSET(a0a, a0b, b0a, b0b, 0)
    LOADSET(a1a, a1b, b1a, b1b, 1)
    WRITESET(0, a0a, a0b, b0a, b0b)
    __syncthreads();

    for (int i = 0; i < 8; i += 2) {
        if (i + 2 < 8) LOADSET(a0a, a0b, b0a, b0b, i + 2)
        COMPUTE(0)
        WRITESET(1, a1a, a1b, b1a, b1b)
        __syncthreads();
        if (i + 3 < 8) LOADSET(a1a, a1b, b1a, b1b, i + 3)
        COMPUTE(1)
        if (i + 2 < 8) WRITESET(0, a0a, a0b, b0a, b0b)
        __syncthreads();
    }

    // epilogue: h2b bf16; D layout: col = lane&15, row = quad*4+reg
#pragma unroll
    for (int t = 0; t < 4; t++)
#pragma unroll
        for (int reg = 0; reg < 4; reg++) {
            int r = row0 + w * 16 + quad * 4 + reg;
            h2b[(size_t)r * 512 + head * 64 + t * 16 + m] = f2bf(acc[t][reg]);
        }

    float as[4], ad[4];
    if (gis32) {
        const float* af32 = (const float*)a_raw + head * 128;
#pragma unroll
        for (int t = 0; t < 4; t++) {
            as[t] = af32[t * 16 + m];
            ad[t] = af32[64 + t * 16 + m];
        }
    } else {
        const unsigned short* ab = (const unsigned short*)a_raw + head * 128;
#pragma unroll
        for (int t = 0; t < 4; t++) {
            as[t] = bf2f(ab[t * 16 + m]);
            ad[t] = bf2f(ab[64 + t * 16 + m]);
        }
    }
#pragma unroll
    for (int reg = 0; reg < 4; reg++) {
        float s1 = as[0] * acc[0][reg] + as[1] * acc[1][reg] + as[2] * acc[2][reg] + as[3] * acc[3][reg];
        float s2 = ad[0] * acc[0][reg] + ad[1] * acc[1][reg] + ad[2] * acc[2][reg] + ad[3] * acc[3][reg];
#pragma unroll
        for (int d = 1; d < 16; d <<= 1) {
            s1 += __shfl_xor(s1, d);
            s2 += __shfl_xor(s2, d);
        }
        if (m == 0) {
            int r = row0 + w * 16 + quad * 4 + reg;
            s_src2[(size_t)r * 8 + head] = s1;
            s_dst2[(size_t)r * 8 + head] = s2;
        }
    }
}

// ---------------------------------------------------------------------------
// Kernel 3: attention + aggregation + row softmax — BYTE-EXACT r12 (frozen).
// ---------------------------------------------------------------------------
__global__ __launch_bounds__(256) void attn_out(const unsigned short* __restrict__ h2b,
                                                const float* __restrict__ s_src2,
                                                const float* __restrict__ s_dst2,
                                                const unsigned long long* __restrict__ adj,
                                                void* __restrict__ out_raw,
                                                const int* __restrict__ flags) {
    __shared__ unsigned short nbrs[4096];
    __shared__ float w_lds[256 * 8];
    __shared__ float sss[8], smax[8], sden[8];
    __shared__ float sredw[4][8];
    __shared__ float sr[8];
    __shared__ int s_cnt;

    int i = blockIdx.x;
    int tid = threadIdx.x;
    int lane = tid & 63, wid = tid >> 6;

    if (tid < 64) {
        unsigned long long word = adj[(size_t)i * 64 + tid];
        int cnt = __popcll(word);
        int incl = cnt;
#pragma unroll
        for (int d = 1; d < 64; d <<= 1) {
            int v = __shfl_up(incl, d);
            if (tid >= d) incl += v;
        }
        int off = incl - cnt;
        unsigned long long w = word;
        int base = tid * 64;
        while (w) {
            int b = __ffsll((unsigned long long)w) - 1;
            nbrs[off++] = (unsigned short)(base + b);
            w &= w - 1;
        }
        if (tid == 63) s_cnt = incl;
    }
    if (tid >= 64 && tid < 72) sss[tid - 64] = s_src2[(size_t)i * 8 + (tid - 64)];
    __syncthreads();
    int cnt = s_cnt;

    int hw = tid & 7;
    float mp = -1e30f;
    for (int t = tid; t < cnt * 8; t += 256)
        mp = fmaxf(mp, s_dst2[(size_t)nbrs[t >> 3] * 8 + hw]);
    mp = fmaxf(mp, __shfl_down(mp, 32));
    mp = fmaxf(mp, __shfl_down(mp, 16));
    mp = fmaxf(mp, __shfl_down(mp, 8));
    if (lane < 8) sredw[wid][lane] = mp;
    __syncthreads();
    if (tid < 8) {
        float m = fmaxf(fmaxf(sredw[0][tid], sredw[1][tid]), fmaxf(sredw[2][tid], sredw[3][tid]));
        float pre = sss[tid] + m;
        smax[tid] = pre > 0.f ? pre : ALPHA * pre;
    }
    __syncthreads();

    int hh = tid >> 5;
    float ssrc_w = sss[hw], maxe_w = smax[hw];
    float den = 0.f, ax = 0.f, ay = 0.f;
    for (int c0 = 0; c0 < cnt; c0 += 256) {
        int csz = min(256, cnt - c0);
        __syncthreads();
        for (int t = tid; t < csz * 8; t += 256) {
            int j = nbrs[c0 + (t >> 3)];
            float e = ssrc_w + s_dst2[(size_t)j * 8 + hw];
            e = e > 0.f ? e : ALPHA * e;
            float w = __expf(e - maxe_w);
            w_lds[t] = w;
            den += w;
        }
        __syncthreads();
#pragma unroll 2
        for (int jj = 0; jj < csz; jj++) {
            int j = nbrs[c0 + jj];
            unsigned int u = *(const unsigned int*)(h2b + (size_t)j * 512 + tid * 2);
            float w = w_lds[jj * 8 + hh];
            ax += w * bf2f((unsigned short)(u & 0xffffu));
            ay += w * bf2f((unsigned short)(u >> 16));
        }
    }

    den += __shfl_down(den, 32);
    den += __shfl_down(den, 16);
    den += __shfl_down(den, 8);
    if (lane < 8) sredw[wid][lane] = den;
    __syncthreads();
    if (tid < 8) sden[tid] = sredw[0][tid] + sredw[1][tid] + sredw[2][tid] + sredw[3][tid];
    __syncthreads();
    float dtot = sden[hh];
    float o0 = ax / dtot, o1 = ay / dtot;

    float m2 = fmaxf(o0, o1);
#pragma unroll
    for (int d = 32; d; d >>= 1) m2 = fmaxf(m2, __shfl_down(m2, d));
    if (lane == 0) sr[wid] = m2;
    __syncthreads();
    float m = fmaxf(fmaxf(sr[0], sr[1]), fmaxf(sr[2], sr[3]));
    float e0 = __expf(o0 - m), e1 = __expf(o1 - m);
    float s = e0 + e1;
#pragma unroll
    for (int d = 32; d; d >>= 1) s += __shfl_down(s, d);
    __syncthreads();
    if (lane == 0) sr[wid + 4] = s;
    __syncthreads();
    s = sr[4] + sr[5] + sr[6] + sr[7];

    if (flags[0]) {
        float2* out = (float2*)out_raw;
        out[(size_t)i * 256 + tid] = make_float2(e0 / s, e1 / s);
    } else {
        unsigned int* out = (unsigned int*)out_raw;
        out[(size_t)i * 256 + tid] = (unsigned int)f2bf(e0 / s) | ((unsigned int)f2bf(e1 / s) << 16);
    }
}

// ---------------------------------------------------------------------------
extern "C" void kernel_launch(void* const* d_in, const int* in_sizes, int n_in,
                              void* d_out, int out_size, void* d_ws, size_t ws_size,
                              hipStream_t stream) {
    const int N = 4096, H = 8;
    const int E = in_sizes[1] / 2;

    const void* x = d_in[0];
    const int*  ei = (const int*)d_in[1];
    const void* W = d_in[2];
    const void* a = d_in[3];

    char* ws = (char*)d_ws;
    unsigned short* h2b = (unsigned short*)ws;                           // 4 MB
    float* s_src2 = (float*)(ws + (size_t)4 * 1024 * 1024);              // 128 KB
    float* s_dst2 = s_src2 + (size_t)N * H;                              // 128 KB
    unsigned long long* adj = (unsigned long long*)(ws + (size_t)5 * 1024 * 1024); // 2 MB
    int* flags = (int*)(ws + (size_t)7 * 1024 * 1024 + 512 * 1024);
    unsigned short* wt_hi = (unsigned short*)(ws + (size_t)8 * 1024 * 1024);       // 512 KB

    hipMemsetAsync(adj, 0, (size_t)N * (N / 8), stream);

    int adj_blocks = (E + N + 255) / 256;
    prep<<<64 + adj_blocks, 256, 0, stream>>>(x, W, ei, E, N, wt_hi, adj, flags);
    gemm_mfma<<<dim3(N / 64, H), 256, 0, stream>>>(x, wt_hi, a,
                                                   h2b, s_src2, s_dst2, flags);
    attn_out<<<N, 256, 0, stream>>>(h2b, s_src2, s_dst2, adj, d_out, flags);
}

// Round 17
// 105.139 us; speedup vs baseline: 1.0199x; 1.0199x over previous
//
#include <hip/hip_runtime.h>

#define ALPHA 0.2f

typedef __attribute__((ext_vector_type(8))) short short8;
typedef __attribute__((ext_vector_type(8))) unsigned short ushort8;
typedef __attribute__((ext_vector_type(4))) float f32x4;

__device__ __forceinline__ float bf2f(unsigned short u) {
    return __uint_as_float(((unsigned int)u) << 16);
}
__device__ __forceinline__ unsigned short f2bf(float f) {
    unsigned int x = __float_as_uint(f);
    unsigned int r = (x + 0x7fffu + ((x >> 16) & 1u)) >> 16;   // RNE
    return (unsigned short)r;
}

// Per-wave fp32-vs-bf16 detection on x's low u16 bf16-exponent plausibility.
__device__ __forceinline__ int detect_is32(const unsigned int* xw) {
    int lane = threadIdx.x & 63;
    unsigned int u = xw[lane];
    unsigned int e = (u >> 7) & 0xffu;
    unsigned long long b = __ballot(e >= 0x58u && e <= 0x90u);
    return (__popcll(b) < 40) ? 1 : 0;
}

// ---------------------------------------------------------------------------
// Kernel 1 (fused prep):
//   blocks [0,1024):    x -> bf16 plane [N][C]
//   blocks [1024,1088): W -> bf16 TRANSPOSED [H][F][C], LDS-tiled
//   blocks [1088,...):  adjacency bitmask atomics (self-detects int64/int32)
// Precision note: lo-planes dropped entirely — the xl*w and x*wl terms are
// both rel-2^-9-class perturbations, below the h2b bf16 rounding floor that
// dominates output error (absmax was bit-stable when xl*w was removed, r14).
// ---------------------------------------------------------------------------
__global__ __launch_bounds__(256) void prep(const void* __restrict__ x_raw,
                                            const void* __restrict__ W_raw,
                                            const int* __restrict__ ei, int E, int N,
                                            unsigned short* __restrict__ x_hi,
                                            unsigned short* __restrict__ wt_hi,
                                            unsigned long long* __restrict__ adj,
                                            int* __restrict__ flags) {
    int bid = blockIdx.x, tid = threadIdx.x;

    if (bid < 1024) {
        int is32 = detect_is32((const unsigned int*)x_raw);
        if (bid == 0 && tid == 0) flags[0] = is32;
        size_t base = ((size_t)bid * 256 + tid) * 8;
        ushort8 h8;
        if (is32) {
            const float* xf = (const float*)x_raw;
            float4 v0 = *(const float4*)(xf + base);
            float4 v1 = *(const float4*)(xf + base + 4);
            float v[8] = {v0.x, v0.y, v0.z, v0.w, v1.x, v1.y, v1.z, v1.w};
#pragma unroll
            for (int j = 0; j < 8; j++) h8[j] = f2bf(v[j]);
        } else {
            const ushort8* xb = (const ushort8*)x_raw;
            h8 = xb[base / 8];
        }
        *(ushort8*)(x_hi + base) = h8;
    } else if (bid < 1088) {
        __shared__ unsigned short lh[64][65];
        int is32 = detect_is32((const unsigned int*)x_raw);
        int b2 = bid - 1024;
        int head = b2 >> 3;
        int c0 = (b2 & 7) * 64;
        int cl = tid >> 2;
        int fc = (tid & 3) * 16;

        size_t ebase = ((size_t)head * 512 + c0 + cl) * 64 + fc;
        if (is32) {
            const float* Wf = (const float*)W_raw;
#pragma unroll
            for (int v4 = 0; v4 < 4; v4++) {
                float4 v = *(const float4*)(Wf + ebase + v4 * 4);
                lh[fc + v4 * 4 + 0][cl] = f2bf(v.x);
                lh[fc + v4 * 4 + 1][cl] = f2bf(v.y);
                lh[fc + v4 * 4 + 2][cl] = f2bf(v.z);
                lh[fc + v4 * 4 + 3][cl] = f2bf(v.w);
            }
        } else {
            const unsigned short* Wb = (const unsigned short*)W_raw;
            ushort8 u0 = *(const ushort8*)(Wb + ebase);
            ushort8 u1 = *(const ushort8*)(Wb + ebase + 8);
#pragma unroll
            for (int k = 0; k < 8; k++) {
                lh[fc + k][cl] = u0[k];
                lh[fc + 8 + k][cl] = u1[k];
            }
        }
        __syncthreads();
        int fl = tid >> 2;
        int cc = (tid & 3) * 16;
        ushort8 oh0, oh1;
#pragma unroll
        for (int k = 0; k < 8; k++) {
            oh0[k] = lh[fl][cc + k];
            oh1[k] = lh[fl][cc + 8 + k];
        }
        size_t o = (size_t)head * 32768 + (size_t)fl * 512 + c0 + cc;
        *(ushort8*)(wt_hi + o)     = oh0;
        *(ushort8*)(wt_hi + o + 8) = oh1;
    } else {
        int lane = tid & 63;
        unsigned long long nz = __ballot(ei[2 * lane + 1] != 0);
        int is64 = (nz == 0ull) ? 1 : 0;
        int t = (bid - 1088) * 256 + tid;
        int words = N >> 6;
        if (t < E) {
            int r = is64 ? ei[2 * t]       : ei[t];
            int c = is64 ? ei[2 * (E + t)] : ei[E + t];
            atomicOr(&adj[(size_t)r * words + (c >> 6)], 1ull << (c & 63));
        } else if (t < E + N) {
            int i = t - E;
            atomicOr(&adj[(size_t)i * words + (i >> 6)], 1ull << (i & 63));
        }
    }
}

// ---------------------------------------------------------------------------
// Kernel 2: MFMA GEMM, pure bf16: h = xh * wh. BK=64, shared LDS
// double-buffer (frozen r8/r12 skeleton), K = 512 -> 8 iters.
// ---------------------------------------------------------------------------
#define LROW 72
__global__ __launch_bounds__(256) void gemm_mfma(const unsigned short* __restrict__ xh,
                                                 const unsigned short* __restrict__ wth,
                                                 const void* __restrict__ a_raw,
                                                 unsigned short* __restrict__ h2b,
                                                 float* __restrict__ s_src2,
                                                 float* __restrict__ s_dst2,
                                                 const int* __restrict__ flags) {
    __shared__ unsigned short sA[2][64 * LROW];
    __shared__ unsigned short sB[2][64 * LROW];

    int head = blockIdx.y;
    int row0 = blockIdx.x * 64;
    int tid = threadIdx.x;
    int w = tid >> 6, lane = tid & 63;
    int m = lane & 15, quad = lane >> 4;
    int srow = tid >> 2, sc = tid & 3;

    size_t baseA = (size_t)(row0 + srow) * 512 + sc * 8;
    size_t baseB = (size_t)head * 32768 + (size_t)srow * 512 + sc * 8;

    int ldsw  = srow * LROW + sc * 8;
    int ldsAr = (w * 16 + m) * LROW + quad * 8;

    f32x4 acc[4] = {f32x4{0.f, 0.f, 0.f, 0.f}, f32x4{0.f, 0.f, 0.f, 0.f},
                    f32x4{0.f, 0.f, 0.f, 0.f}, f32x4{0.f, 0.f, 0.f, 0.f}};

    // iter c (0..7): k-offset c*64.
#define LOADSET(Aa, Ab, Ba, Bb, c)                                         \
    {                                                                      \
        size_t ko = (size_t)(c) * 64;                                      \
        Aa = *(const ushort8*)(xh + baseA + ko);                           \
        Ab = *(const ushort8*)(xh + baseA + ko + 32);                      \
        Ba = *(const ushort8*)(wth + baseB + ko);                          \
        Bb = *(const ushort8*)(wth + baseB + ko + 32);                     \
    }

#define WRITESET(buf, Aa, Ab, Ba, Bb)                                      \
    {                                                                      \
        *(ushort8*)&sA[buf][ldsw]      = Aa;                               \
        *(ushort8*)&sA[buf][ldsw + 32] = Ab;                               \
        *(ushort8*)&sB[buf][ldsw]      = Ba;                               \
        *(ushort8*)&sB[buf][ldsw + 32] = Bb;                               \
    }

#define COMPUTE(buf)                                                       \
    {                                                                      \
        short8 af0 = *(const short8*)&sA[buf][ldsAr];                      \
        short8 af1 = *(const short8*)&sA[buf][ldsAr + 32];                 \
        _Pragma("unroll")                                                  \
        for (int t = 0; t < 4; t++) {                                      \
            int bo = (t * 16 + m) * LROW + quad * 8;                       \
            short8 bf0 = *(const short8*)&sB[buf][bo];                     \
            short8 bf1 = *(const short8*)&sB[buf][bo + 32];                \
            acc[t] = __builtin_amdgcn_mfma_f32_16x16x32_bf16(af0, bf0, acc[t], 0, 0, 0); \
            acc[t] = __builtin_amdgcn_mfma_f32_16x16x32_bf16(af1, bf1, acc[t], 0, 0, 0); \
        }                                                                  \
    }

    ushort8 a0a, a0b, b0a, b0b;    // even set
    ushort8 a1a, a1b, b1a, b1b;    // odd set

    LOADSET(a0a, a0b, b0a, b0b, 0)
    LOADSET(a1a, a1b, b1a, b1b, 1)
    WRITESET(0, a0a, a0b, b0a, b0b)
    __syncthreads();

    for (int i = 0; i < 8; i += 2) {
        if (i + 2 < 8) LOADSET(a0a, a0b, b0a, b0b, i + 2)
        COMPUTE(0)
        WRITESET(1, a1a, a1b, b1a, b1b)
        __syncthreads();
        if (i + 3 < 8) LOADSET(a1a, a1b, b1a, b1b, i + 3)
        COMPUTE(1)
        if (i + 2 < 8) WRITESET(0, a0a, a0b, b0a, b0b)
        __syncthreads();
    }

    // epilogue: h2b bf16; D layout: col = lane&15, row = quad*4+reg
#pragma unroll
    for (int t = 0; t < 4; t++)
#pragma unroll
        for (int reg = 0; reg < 4; reg++) {
            int r = row0 + w * 16 + quad * 4 + reg;
            h2b[(size_t)r * 512 + head * 64 + t * 16 + m] = f2bf(acc[t][reg]);
        }

    float as[4], ad[4];
    if (flags[0]) {
        const float* af32 = (const float*)a_raw + head * 128;
#pragma unroll
        for (int t = 0; t < 4; t++) {
            as[t] = af32[t * 16 + m];
            ad[t] = af32[64 + t * 16 + m];
        }
    } else {
        const unsigned short* ab = (const unsigned short*)a_raw + head * 128;
#pragma unroll
        for (int t = 0; t < 4; t++) {
            as[t] = bf2f(ab[t * 16 + m]);
            ad[t] = bf2f(ab[64 + t * 16 + m]);
        }
    }
#pragma unroll
    for (int reg = 0; reg < 4; reg++) {
        float s1 = as[0] * acc[0][reg] + as[1] * acc[1][reg] + as[2] * acc[2][reg] + as[3] * acc[3][reg];
        float s2 = ad[0] * acc[0][reg] + ad[1] * acc[1][reg] + ad[2] * acc[2][reg] + ad[3] * acc[3][reg];
#pragma unroll
        for (int d = 1; d < 16; d <<= 1) {
            s1 += __shfl_xor(s1, d);
            s2 += __shfl_xor(s2, d);
        }
        if (m == 0) {
            int r = row0 + w * 16 + quad * 4 + reg;
            s_src2[(size_t)r * 8 + head] = s1;
            s_dst2[(size_t)r * 8 + head] = s2;
        }
    }
}

// ---------------------------------------------------------------------------
// Kernel 3: attention + aggregation + row softmax — BYTE-EXACT r12 (frozen).
// ---------------------------------------------------------------------------
__global__ __launch_bounds__(256) void attn_out(const unsigned short* __restrict__ h2b,
                                                const float* __restrict__ s_src2,
                                                const float* __restrict__ s_dst2,
                                                const unsigned long long* __restrict__ adj,
                                                void* __restrict__ out_raw,
                                                const int* __restrict__ flags) {
    __shared__ unsigned short nbrs[4096];
    __shared__ float w_lds[256 * 8];
    __shared__ float sss[8], smax[8], sden[8];
    __shared__ float sredw[4][8];
    __shared__ float sr[8];
    __shared__ int s_cnt;

    int i = blockIdx.x;
    int tid = threadIdx.x;
    int lane = tid & 63, wid = tid >> 6;

    if (tid < 64) {
        unsigned long long word = adj[(size_t)i * 64 + tid];
        int cnt = __popcll(word);
        int incl = cnt;
#pragma unroll
        for (int d = 1; d < 64; d <<= 1) {
            int v = __shfl_up(incl, d);
            if (tid >= d) incl += v;
        }
        int off = incl - cnt;
        unsigned long long w = word;
        int base = tid * 64;
        while (w) {
            int b = __ffsll((unsigned long long)w) - 1;
            nbrs[off++] = (unsigned short)(base + b);
            w &= w - 1;
        }
        if (tid == 63) s_cnt = incl;
    }
    if (tid >= 64 && tid < 72) sss[tid - 64] = s_src2[(size_t)i * 8 + (tid - 64)];
    __syncthreads();
    int cnt = s_cnt;

    int hw = tid & 7;
    float mp = -1e30f;
    for (int t = tid; t < cnt * 8; t += 256)
        mp = fmaxf(mp, s_dst2[(size_t)nbrs[t >> 3] * 8 + hw]);
    mp = fmaxf(mp, __shfl_down(mp, 32));
    mp = fmaxf(mp, __shfl_down(mp, 16));
    mp = fmaxf(mp, __shfl_down(mp, 8));
    if (lane < 8) sredw[wid][lane] = mp;
    __syncthreads();
    if (tid < 8) {
        float m = fmaxf(fmaxf(sredw[0][tid], sredw[1][tid]), fmaxf(sredw[2][tid], sredw[3][tid]));
        float pre = sss[tid] + m;
        smax[tid] = pre > 0.f ? pre : ALPHA * pre;
    }
    __syncthreads();

    int hh = tid >> 5;
    float ssrc_w = sss[hw], maxe_w = smax[hw];
    float den = 0.f, ax = 0.f, ay = 0.f;
    for (int c0 = 0; c0 < cnt; c0 += 256) {
        int csz = min(256, cnt - c0);
        __syncthreads();
        for (int t = tid; t < csz * 8; t += 256) {
            int j = nbrs[c0 + (t >> 3)];
            float e = ssrc_w + s_dst2[(size_t)j * 8 + hw];
            e = e > 0.f ? e : ALPHA * e;
            float w = __expf(e - maxe_w);
            w_lds[t] = w;
            den += w;
        }
        __syncthreads();
#pragma unroll 2
        for (int jj = 0; jj < csz; jj++) {
            int j = nbrs[c0 + jj];
            unsigned int u = *(const unsigned int*)(h2b + (size_t)j * 512 + tid * 2);
            float w = w_lds[jj * 8 + hh];
            ax += w * bf2f((unsigned short)(u & 0xffffu));
            ay += w * bf2f((unsigned short)(u >> 16));
        }
    }

    den += __shfl_down(den, 32);
    den += __shfl_down(den, 16);
    den += __shfl_down(den, 8);
    if (lane < 8) sredw[wid][lane] = den;
    __syncthreads();
    if (tid < 8) sden[tid] = sredw[0][tid] + sredw[1][tid] + sredw[2][tid] + sredw[3][tid];
    __syncthreads();
    float dtot = sden[hh];
    float o0 = ax / dtot, o1 = ay / dtot;

    float m2 = fmaxf(o0, o1);
#pragma unroll
    for (int d = 32; d; d >>= 1) m2 = fmaxf(m2, __shfl_down(m2, d));
    if (lane == 0) sr[wid] = m2;
    __syncthreads();
    float m = fmaxf(fmaxf(sr[0], sr[1]), fmaxf(sr[2], sr[3]));
    float e0 = __expf(o0 - m), e1 = __expf(o1 - m);
    float s = e0 + e1;
#pragma unroll
    for (int d = 32; d; d >>= 1) s += __shfl_down(s, d);
    __syncthreads();
    if (lane == 0) sr[wid + 4] = s;
    __syncthreads();
    s = sr[4] + sr[5] + sr[6] + sr[7];

    if (flags[0]) {
        float2* out = (float2*)out_raw;
        out[(size_t)i * 256 + tid] = make_float2(e0 / s, e1 / s);
    } else {
        unsigned int* out = (unsigned int*)out_raw;
        out[(size_t)i * 256 + tid] = (unsigned int)f2bf(e0 / s) | ((unsigned int)f2bf(e1 / s) << 16);
    }
}

// ---------------------------------------------------------------------------
extern "C" void kernel_launch(void* const* d_in, const int* in_sizes, int n_in,
                              void* d_out, int out_size, void* d_ws, size_t ws_size,
                              hipStream_t stream) {
    const int N = 4096, H = 8;
    const int E = in_sizes[1] / 2;

    const void* x = d_in[0];
    const int*  ei = (const int*)d_in[1];
    const void* W = d_in[2];
    const void* a = d_in[3];

    char* ws = (char*)d_ws;
    unsigned short* h2b = (unsigned short*)ws;                           // 4 MB
    float* s_src2 = (float*)(ws + (size_t)4 * 1024 * 1024);              // 128 KB
    float* s_dst2 = s_src2 + (size_t)N * H;                              // 128 KB
    unsigned long long* adj = (unsigned long long*)(ws + (size_t)5 * 1024 * 1024); // 2 MB
    int* flags = (int*)(ws + (size_t)7 * 1024 * 1024 + 512 * 1024);
    unsigned short* x_hi  = (unsigned short*)(ws + (size_t)8 * 1024 * 1024);       // 4 MB
    unsigned short* wt_hi = (unsigned short*)(ws + (size_t)16 * 1024 * 1024);      // 512 KB

    hipMemsetAsync(adj, 0, (size_t)N * (N / 8), stream);

    int adj_blocks = (E + N + 255) / 256;
    prep<<<1088 + adj_blocks, 256, 0, stream>>>(x, W, ei, E, N,
                                                x_hi, wt_hi, adj, flags);
    gemm_mfma<<<dim3(N / 64, H), 256, 0, stream>>>(x_hi, wt_hi, a,
                                                   h2b, s_src2, s_dst2, flags);
    attn_out<<<N, 256, 0, stream>>>(h2b, s_src2, s_dst2, adj, d_out, flags);
}